// Round 7
// baseline (367.861 us; speedup 1.0000x reference)
//
#include <hip/hip_runtime.h>
#include <cstdint>
#include <math.h>

#define L_SEQ 8192
#define DM    1024
#define NQK   2048          // fused Q,K output width

typedef unsigned short u16;
typedef __bf16 bf16;
typedef bf16  bf16x8 __attribute__((ext_vector_type(8)));
typedef float f32x4  __attribute__((ext_vector_type(4)));
typedef float f32x16 __attribute__((ext_vector_type(16)));

__device__ __forceinline__ u16 f2bf(float f) {
    unsigned u = __float_as_uint(f);
    u += 0x7fffu + ((u >> 16) & 1u);
    return (u16)(u >> 16);
}

__device__ __forceinline__ f32x4 mfma16(bf16x8 a, bf16x8 b, f32x4 c) {
    return __builtin_amdgcn_mfma_f32_16x16x32_bf16(a, b, c, 0, 0, 0);
}
__device__ __forceinline__ f32x16 mfma32(bf16x8 a, bf16x8 b, f32x16 c) {
    return __builtin_amdgcn_mfma_f32_32x32x16_bf16(a, b, c, 0, 0, 0);
}

__device__ __forceinline__ void gld_lds16(const u16* g, u16* l) {
    __builtin_amdgcn_global_load_lds((const __attribute__((address_space(1))) void*)g,
                                     (__attribute__((address_space(3))) void*)l,
                                     16, 0, 0);
}

// ---------------- fp32 -> bf16 conversion (8 elems / thread) ----------------
__global__ void cvt_bf16(const float* __restrict__ src, u16* __restrict__ dst, int n8) {
    int i = blockIdx.x * 256 + threadIdx.x;
    if (i >= n8) return;
    const float4* s4 = (const float4*)src;
    float4 a = s4[2 * i], b = s4[2 * i + 1];
    union { uint4 u; u16 h[8]; } r;
    r.h[0] = f2bf(a.x); r.h[1] = f2bf(a.y); r.h[2] = f2bf(a.z); r.h[3] = f2bf(a.w);
    r.h[4] = f2bf(b.x); r.h[5] = f2bf(b.y); r.h[6] = f2bf(b.z); r.h[7] = f2bf(b.w);
    ((uint4*)dst)[i] = r.u;
}

// ---------------- merged prep: 4 weight cvts + RoPE table -------------------
__global__ void prep_misc(const float* __restrict__ wq, const float* __restrict__ wk,
                          const float* __restrict__ wv, const float* __restrict__ wo,
                          u16* __restrict__ wf, u16* __restrict__ wob,
                          float2* __restrict__ rt) {
    int idx = blockIdx.x * 256 + threadIdx.x;      // 0..786431
    if (idx < 524288) {
        int sel = idx >> 17, i = idx & 131071;
        const float* s = sel == 0 ? wq : sel == 1 ? wk : sel == 2 ? wv : wo;
        u16* d        = sel == 0 ? wf : sel == 1 ? wf + 1048576 : sel == 2 ? wf + 2097152 : wob;
        const float4* s4 = (const float4*)s;
        float4 a = s4[2 * i], b = s4[2 * i + 1];
        union { uint4 u; u16 h[8]; } r;
        r.h[0] = f2bf(a.x); r.h[1] = f2bf(a.y); r.h[2] = f2bf(a.z); r.h[3] = f2bf(a.w);
        r.h[4] = f2bf(b.x); r.h[5] = f2bf(b.y); r.h[6] = f2bf(b.z); r.h[7] = f2bf(b.w);
        ((uint4*)d)[i] = r.u;
    } else {
        int j = idx - 524288;                      // 0..262143
        int pos = j >> 5, i = j & 31;
        float invf = exp2f(-0.4152410118609191f * (float)i);   // 10000^(-i/32)
        float s, c;
        sincosf((float)pos * invf, &s, &c);
        rt[j] = make_float2(c, s);
    }
}

// ============================================================================
// Shared geometry: 256M x 128N tile, BK=32, 256 threads = 4 waves (2M x 2N),
// per-wave 128x64. LDS 3-buffer (A 3x16KB + B 3x8KB = 72KB) -> 2 blocks/CU.
// Per iter: waitcnt vmcnt(6)+lgkm(0) -> barrier -> [fence] -> ds_read frags(u+1)
// || stage(u+3) -> MFMA(u).  LDS layout: 128B line = 2 rows x 4 k-chunks,
// chunk-XOR (line&7).  XCD supertile keeps A(4MB)+B L2-resident.
// qkv uses 32x32x16 MFMA + single fence; oproj keeps 16x16x32 (control).
// ============================================================================

#define STAGE_COMMON()                                                         \
    const int tid = threadIdx.x;                                               \
    const int lane = tid & 63, w = tid >> 6;                                   \
    const int wm = w >> 1, wn = w & 1;                                         \
    const u16* gA[4]; const u16* gB[2];                                        \
    _Pragma("unroll")                                                          \
    for (int i = 0; i < 4; ++i) {                                              \
        int s = i * 256 + tid;                                                 \
        int li = s >> 3, pc = s & 7, lc = pc ^ (li & 7);                       \
        int row = 2 * li + (lc >> 2), kc = lc & 3;                             \
        gA[i] = Ap + (size_t)(m0 + row) * DM + kc * 8;                         \
    }                                                                          \
    _Pragma("unroll")                                                          \
    for (int i = 0; i < 2; ++i) {                                              \
        int s = i * 256 + tid;                                                 \
        int li = s >> 3, pc = s & 7, lc = pc ^ (li & 7);                       \
        int row = 2 * li + (lc >> 2), kc = lc & 3;                             \
        gB[i] = Bp + (size_t)(n0 + row) * DM + kc * 8;                         \
    }                                                                          \
    u16* ldsAt = SAs + tid * 8;                                                \
    u16* ldsBt = SBs + tid * 8;                                                \
    /* prologue: stage tiles 0,1,2 into bufs 0,1,2 */                          \
    _Pragma("unroll")                                                          \
    for (int t3 = 0; t3 < 3; ++t3) {                                           \
        _Pragma("unroll")                                                      \
        for (int i = 0; i < 4; ++i) gld_lds16(gA[i] + t3 * 32, ldsAt + t3 * 8192 + i * 2048); \
        _Pragma("unroll")                                                      \
        for (int i = 0; i < 2; ++i) gld_lds16(gB[i] + t3 * 32, ldsBt + t3 * 4096 + i * 2048); \
    }

// ---------------- qkv: 32x32x16 path ----------------------------------------
// A-frag: row = lane&31, k = (lane>>5)*8 + j.  B-frag: col = lane&31, same k.
// C/D: col = lane&31, row = (reg&3) + 8*(reg>>2) + 4*(lane>>5)   [m74/m101]
#define QITER32(U, WIMM, RD, ST) do {                                          \
    __builtin_amdgcn_s_waitcnt(WIMM);                                          \
    __builtin_amdgcn_s_barrier();                                              \
    __builtin_amdgcn_sched_barrier(0);                                         \
    if (RD) {                                                                  \
        _Pragma("unroll")                                                      \
        for (int mt = 0; mt < 4; mt++) {                                       \
            fA[(U + 1) & 1][mt][0] = *(const bf16x8*)(SAs + ((U + 1) % 3) * 8192 + aB + mt * 1024 + pc0 * 8); \
            fA[(U + 1) & 1][mt][1] = *(const bf16x8*)(SAs + ((U + 1) % 3) * 8192 + aB + mt * 1024 + pc1 * 8); \
        }                                                                      \
        _Pragma("unroll")                                                      \
        for (int nt = 0; nt < 2; nt++) {                                       \
            fB[(U + 1) & 1][nt][0] = *(const bf16x8*)(SBs + ((U + 1) % 3) * 4096 + bB + nt * 1024 + pc0 * 8); \
            fB[(U + 1) & 1][nt][1] = *(const bf16x8*)(SBs + ((U + 1) % 3) * 4096 + bB + nt * 1024 + pc1 * 8); \
        }                                                                      \
    }                                                                          \
    if (ST) {                                                                  \
        _Pragma("unroll")                                                      \
        for (int i = 0; i < 4; ++i)                                            \
            gld_lds16(gA[i] + (U + 3) * 32, ldsAt + (U % 3) * 8192 + i * 2048);\
        _Pragma("unroll")                                                      \
        for (int i = 0; i < 2; ++i)                                            \
            gld_lds16(gB[i] + (U + 3) * 32, ldsBt + (U % 3) * 4096 + i * 2048);\
    }                                                                          \
    _Pragma("unroll")                                                          \
    for (int s = 0; s < 2; s++)                                                \
        _Pragma("unroll")                                                      \
        for (int mt = 0; mt < 4; mt++)                                         \
            _Pragma("unroll")                                                  \
            for (int nt = 0; nt < 2; nt++)                                     \
                acc[mt][nt] = mfma32(fA[(U) & 1][mt][s], fB[(U) & 1][nt][s], acc[mt][nt]); \
} while (0)

#define K_LOOP32()                                                             \
    QITER32(0,0x0076,1,1);  QITER32(1,0x0076,1,1);  QITER32(2,0x0076,1,1);     \
    QITER32(3,0x0076,1,1);  QITER32(4,0x0076,1,1);  QITER32(5,0x0076,1,1);     \
    QITER32(6,0x0076,1,1);  QITER32(7,0x0076,1,1);  QITER32(8,0x0076,1,1);     \
    QITER32(9,0x0076,1,1);  QITER32(10,0x0076,1,1); QITER32(11,0x0076,1,1);    \
    QITER32(12,0x0076,1,1); QITER32(13,0x0076,1,1); QITER32(14,0x0076,1,1);    \
    QITER32(15,0x0076,1,1); QITER32(16,0x0076,1,1); QITER32(17,0x0076,1,1);    \
    QITER32(18,0x0076,1,1); QITER32(19,0x0076,1,1); QITER32(20,0x0076,1,1);    \
    QITER32(21,0x0076,1,1); QITER32(22,0x0076,1,1); QITER32(23,0x0076,1,1);    \
    QITER32(24,0x0076,1,1); QITER32(25,0x0076,1,1); QITER32(26,0x0076,1,1);    \
    QITER32(27,0x0076,1,1); QITER32(28,0x0076,1,1); QITER32(29,0x0076,1,0);    \
    QITER32(30,0x0070,1,0); QITER32(31,0x0070,0,0)

__global__ __launch_bounds__(256, 2) void gemm_qkv_fused(
    const u16* __restrict__ X,        // [16384][1024]
    const u16* __restrict__ W,        // [3072][1024] rows: q,k,v stacked
    const float2* __restrict__ rope,  // [8192][32]
    u16* __restrict__ Y,              // [16384][2048]
    u16* __restrict__ Vt)             // [2*16*64][8192]
{
    __shared__ __align__(16) u16 smem[36864];   // 72 KiB
    u16* SAs = smem;                  // 3 x 8192 u16 (A bufs)
    u16* SBs = smem + 24576;          // 3 x 4096 u16 (B bufs)

    // XCD supertile: 1536 blocks; xcd owns 8 m-panels; supertile 8m x 8n
    const int o   = (int)blockIdx.x;
    const int xcd = o & 7;
    const int r   = o >> 3;                     // 0..191
    const int st  = r >> 6;                     // 3 supertiles of 64
    const int t   = r & 63;
    const int m0  = (xcd * 8 + (t & 7)) * 256;  // 64 m-panels
    const int n0  = (st * 8 + (t >> 3)) * 128;  // 24 n-panels

    const u16* Ap = X;
    const u16* Bp = W;
    STAGE_COMMON();

    // fragment-read constants (32x32 mapping)
    const int l31 = lane & 31, hi = lane >> 5;
    const int l2  = l31 >> 1;
    const int p4  = (lane & 1) * 4;
    const int pc0 = (p4 + hi) ^ (l2 & 7);        // k-step 0: chunks 0/1
    const int pc1 = (p4 + 2 + hi) ^ (l2 & 7);    // k-step 1: chunks 2/3
    const int aB  = wm * 4096 + l2 * 64;
    const int bB  = wn * 2048 + l2 * 64;

    const f32x16 fz16 = {0.f,0.f,0.f,0.f,0.f,0.f,0.f,0.f,0.f,0.f,0.f,0.f,0.f,0.f,0.f,0.f};
    f32x16 acc[4][2];
    #pragma unroll
    for (int a = 0; a < 4; a++)
        #pragma unroll
        for (int b = 0; b < 2; b++) acc[a][b] = fz16;
    bf16x8 fA[2][4][2], fB[2][2][2];

    __builtin_amdgcn_s_waitcnt(0x0F7C);  // vmcnt(12): stage(0) landed
    __builtin_amdgcn_s_barrier();
    __builtin_amdgcn_sched_barrier(0);
    #pragma unroll
    for (int mt = 0; mt < 4; mt++) {
        fA[0][mt][0] = *(const bf16x8*)(SAs + aB + mt * 1024 + pc0 * 8);
        fA[0][mt][1] = *(const bf16x8*)(SAs + aB + mt * 1024 + pc1 * 8);
    }
    #pragma unroll
    for (int nt = 0; nt < 2; nt++) {
        fB[0][nt][0] = *(const bf16x8*)(SBs + bB + nt * 1024 + pc0 * 8);
        fB[0][nt][1] = *(const bf16x8*)(SBs + bB + nt * 1024 + pc1 * 8);
    }

    K_LOOP32();
    __syncthreads();

    if (n0 < 2048) {
        // RoPE: col = wn*64 + nt*32 + l31; pair (i,i+32) = nt 0 vs 1, freq = l31
        #pragma unroll
        for (int mt = 0; mt < 4; mt++)
            #pragma unroll
            for (int reg = 0; reg < 16; reg++) {
                int crr = (reg & 3) + 8 * (reg >> 2) + 4 * hi;
                int rg = (m0 + wm * 128 + mt * 32 + crr) & (L_SEQ - 1);
                float2 cs = rope[rg * 32 + l31];
                float x1 = acc[mt][0][reg], x2 = acc[mt][1][reg];
                acc[mt][0][reg] = x1 * cs.x - x2 * cs.y;
                acc[mt][1][reg] = x2 * cs.x + x1 * cs.y;
            }
        // store via LDS, two 128-row passes
        u16* Es = smem;   // [128][136]
        #pragma unroll
        for (int mh = 0; mh < 2; mh++) {
            if (mh) __syncthreads();
            if (wm == mh) {
                #pragma unroll
                for (int mt = 0; mt < 4; mt++)
                    #pragma unroll
                    for (int nt = 0; nt < 2; nt++)
                        #pragma unroll
                        for (int reg = 0; reg < 16; reg++) {
                            int crr = (reg & 3) + 8 * (reg >> 2) + 4 * hi;
                            Es[(mt * 32 + crr) * 136 + wn * 64 + nt * 32 + l31] =
                                f2bf(acc[mt][nt][reg]);
                        }
            }
            __syncthreads();
            #pragma unroll
            for (int i = 0; i < 8; i++) {
                int idx = i * 256 + tid;
                int row = idx >> 4, ch = (idx & 15) * 8;
                uint4 v = *(const uint4*)(Es + row * 136 + ch);
                *(uint4*)(Y + (size_t)(m0 + mh * 128 + row) * NQK + n0 + ch) = v;
            }
        }
    } else {
        // V slice: store TRANSPOSED. Two row-half passes: Es[col][row]
        u16* Es = smem;   // [128][136]
        const int bb = m0 >> 13, seq0 = m0 & (L_SEQ - 1);
        #pragma unroll
        for (int rh = 0; rh < 2; rh++) {
            if (rh) __syncthreads();
            if (wm == rh) {
                #pragma unroll
                for (int mt = 0; mt < 4; mt++)
                    #pragma unroll
                    for (int nt = 0; nt < 2; nt++)
                        #pragma unroll
                        for (int reg = 0; reg < 16; reg++) {
                            int crr = (reg & 3) + 8 * (reg >> 2) + 4 * hi;
                            Es[(wn * 64 + nt * 32 + l31) * 136 + mt * 32 + crr] =
                                f2bf(acc[mt][nt][reg]);
                        }
            }
            __syncthreads();
            #pragma unroll
            for (int i = 0; i < 8; i++) {
                int idx = i * 256 + tid;
                int dr = idx >> 4, ch = (idx & 15) * 8;
                int gc = n0 - 2048 + dr;           // global V col = h*64 + d
                uint4 v = *(const uint4*)(Es + dr * 136 + ch);
                *(uint4*)(Vt + (size_t)(bb * 1024 + gc) * L_SEQ + seq0 + rh * 128 + ch) = v;
            }
        }
    }
}

// ---------------- oproj: 16x16x32 path (round-6 control) ---------------------
#define QITER(U, WIMM, RD, ST) do {                                            \
    __builtin_amdgcn_s_waitcnt(WIMM);                                          \
    __builtin_amdgcn_sched_barrier(0);                                         \
    __builtin_amdgcn_s_barrier();                                              \
    __builtin_amdgcn_sched_barrier(0);                                         \
    if (RD) {                                                                  \
        _Pragma("unroll")                                                      \
        for (int m = 0; m < 8; m++)                                            \
            fA[(U + 1) & 1][m] = *(const bf16x8*)(SAs + ((U + 1) % 3) * 8192 + aBase + m * 512); \
        _Pragma("unroll")                                                      \
        for (int n = 0; n < 4; n++)                                            \
            fB[(U + 1) & 1][n] = *(const bf16x8*)(SBs + ((U + 1) % 3) * 4096 + bBase + n * 512); \
    }                                                                          \
    if (ST) {                                                                  \
        _Pragma("unroll")                                                      \
        for (int i = 0; i < 4; ++i)                                            \
            gld_lds16(gA[i] + (U + 3) * 32, ldsAt + (U % 3) * 8192 + i * 2048);\
        _Pragma("unroll")                                                      \
        for (int i = 0; i < 2; ++i)                                            \
            gld_lds16(gB[i] + (U + 3) * 32, ldsBt + (U % 3) * 4096 + i * 2048);\
    }                                                                          \
    __builtin_amdgcn_sched_barrier(0);                                         \
    __builtin_amdgcn_s_setprio(1);                                             \
    _Pragma("unroll")                                                          \
    for (int m = 0; m < 8; m++)                                                \
        _Pragma("unroll")                                                      \
        for (int n = 0; n < 4; n++)                                            \
            acc[m][n] = mfma16(fA[(U) & 1][m], fB[(U) & 1][n], acc[m][n]);     \
    __builtin_amdgcn_s_setprio(0);                                             \
    __builtin_amdgcn_sched_barrier(0);                                         \
} while (0)

#define K_LOOP_ALL()                                                           \
    QITER(0,0x0076,1,1);  QITER(1,0x0076,1,1);  QITER(2,0x0076,1,1);           \
    QITER(3,0x0076,1,1);  QITER(4,0x0076,1,1);  QITER(5,0x0076,1,1);           \
    QITER(6,0x0076,1,1);  QITER(7,0x0076,1,1);  QITER(8,0x0076,1,1);           \
    QITER(9,0x0076,1,1);  QITER(10,0x0076,1,1); QITER(11,0x0076,1,1);          \
    QITER(12,0x0076,1,1); QITER(13,0x0076,1,1); QITER(14,0x0076,1,1);          \
    QITER(15,0x0076,1,1); QITER(16,0x0076,1,1); QITER(17,0x0076,1,1);          \
    QITER(18,0x0076,1,1); QITER(19,0x0076,1,1); QITER(20,0x0076,1,1);          \
    QITER(21,0x0076,1,1); QITER(22,0x0076,1,1); QITER(23,0x0076,1,1);          \
    QITER(24,0x0076,1,1); QITER(25,0x0076,1,1); QITER(26,0x0076,1,1);          \
    QITER(27,0x0076,1,1); QITER(28,0x0076,1,1); QITER(29,0x0076,1,0);          \
    QITER(30,0x0070,1,0); QITER(31,0x0070,0,0)

__global__ __launch_bounds__(256, 2) void gemm_oproj(
    const u16* __restrict__ A,        // [16384][1024] bf16
    const u16* __restrict__ Wo,       // [1024][1024] bf16
    const float* __restrict__ bias,
    float* __restrict__ Out)
{
    __shared__ __align__(16) u16 smem[36864];   // 72 KiB
    u16* SAs = smem;
    u16* SBs = smem + 24576;

    // 512 blocks: one 8m x 8n supertile per XCD
    const int o   = (int)blockIdx.x;
    const int xcd = o & 7;
    const int t   = o >> 3;                     // 0..63
    const int m0  = (xcd * 8 + (t & 7)) * 256;
    const int n0  = (t >> 3) * 128;

    const u16* Ap = A;
    const u16* Bp = Wo;
    STAGE_COMMON();

    const int quad = lane >> 4, ln = lane & 15;
    const int l7  = (ln >> 1) & 7;
    const int pcq = ((ln & 1) * 4 + quad) ^ l7;
    const int aBase = (wm * 64 + (ln >> 1)) * 64 + pcq * 8;
    const int bBase = (wn * 32 + (ln >> 1)) * 64 + pcq * 8;

    const f32x4 fz = {0.f, 0.f, 0.f, 0.f};
    f32x4 acc[8][4];
    #pragma unroll
    for (int a = 0; a < 8; a++)
        #pragma unroll
        for (int b = 0; b < 4; b++) acc[a][b] = fz;
    bf16x8 fA[2][8], fB[2][4];

    __builtin_amdgcn_s_waitcnt(0x0F7C);  // vmcnt(12): stage(0) landed
    __builtin_amdgcn_s_barrier();
    __builtin_amdgcn_sched_barrier(0);
    #pragma unroll
    for (int m = 0; m < 8; m++) fA[0][m] = *(const bf16x8*)(SAs + aBase + m * 512);
    #pragma unroll
    for (int n = 0; n < 4; n++) fB[0][n] = *(const bf16x8*)(SBs + bBase + n * 512);

    K_LOOP_ALL();
    __syncthreads();

    // epilogue: bias + fp32 store via LDS, four 64-row passes
    float b4[4];
    #pragma unroll
    for (int nt = 0; nt < 4; nt++) b4[nt] = bias[n0 + wn * 64 + nt * 16 + ln];

    float* Ef = (float*)smem;   // [64][132]
    #pragma unroll
    for (int mq = 0; mq < 4; mq++) {
        if (mq) __syncthreads();
        if (wm == (mq >> 1)) {
            #pragma unroll
            for (int mt = 0; mt < 4; mt++)
                #pragma unroll
                for (int nt = 0; nt < 4; nt++)
                    #pragma unroll
                    for (int reg = 0; reg < 4; reg++)
                        Ef[(mt * 16 + quad * 4 + reg) * 132 + wn * 64 + nt * 16 + ln] =
                            acc[(mq & 1) * 4 + mt][nt][reg] + b4[nt];
        }
        __syncthreads();
        #pragma unroll
        for (int i = 0; i < 8; i++) {
            int idx = i * 256 + tid;
            int row = idx >> 5, ch = (idx & 31) * 4;
            float4 v = *(const float4*)(Ef + row * 132 + ch);
            *(float4*)(Out + (size_t)(m0 + mq * 64 + row) * DM + n0 + ch) = v;
        }
    }
}

// ---------------- Windowed attention ----------------------------------------
// WG = 512 threads / 8 waves = 128 queries x 1 head. grid (64, 16, 2).
// K and V^T staged once per WG via global_load_lds (XOR chunk swizzle).
__global__ __launch_bounds__(512, 4) void attn(
    const u16* __restrict__ QK,       // [16384][2048]
    const u16* __restrict__ Vt,       // [2048][8192]
    u16* __restrict__ AO)             // [16384][1024]
{
    __shared__ __align__(16) u16 Ks[256 * 64];     // [key][dim-chunk swizzled] 32KB (aliased by AOs)
    __shared__ __align__(16) u16 Vs[64 * 256];     // [dim][key-chunk swizzled] 32KB
    __shared__ __align__(16) u16 pbuf[8][512];     // per-wave P chunk, xor-swizzled

    const int blk = blockIdx.x;
    const int h   = blockIdx.y;
    const int b   = blockIdx.z;
    const int tid = threadIdx.x;
    const int lane = tid & 63, w = tid >> 6;
    const int quad = lane >> 4, ln = lane & 15;
    const int wstart = blk * 128 - 64;
    const size_t bbase = (size_t)b * L_SEQ;

    const u16* Kg = QK + 1024 + h * 64;
    const u16* Vg = Vt + (size_t)(b * 1024 + h * 64) * L_SEQ;

    // stage K: 256 rows x 8 chunks, chunk cg = cl ^ (row&7)
    #pragma unroll
    for (int i = 0; i < 4; i++) {
        int c = i * 512 + tid;
        int row = c >> 3, cl = c & 7, cg = cl ^ (row & 7);
        int kr = wstart + row;
        kr = kr < 0 ? 0 : (kr > L_SEQ - 1 ? L_SEQ - 1 : kr);
        gld_lds16(Kg + (size_t)(bbase + kr) * NQK + cg * 8, Ks + c * 8);
    }
    // stage V^T: 64 dim-rows x 32 key-chunks, chunk cg = kc ^ (d&7)
    #pragma unroll
    for (int i = 0; i < 4; i++) {
        int c = i * 512 + tid;
        int d = c >> 5, kc = c & 31, cg = kc ^ (d & 7);
        int key = wstart + cg * 8;
        key = key < 0 ? 0 : (key > L_SEQ - 8 ? L_SEQ - 8 : key);
        gld_lds16(Vg + (size_t)d * L_SEQ + key, Vs + c * 8);
    }

    // Q fragments (A-layout: m=ln, k=quad*8+j) direct from global
    const int qrow = blk * 128 + w * 16 + ln;
    const u16* qp = QK + (bbase + qrow) * NQK + h * 64 + quad * 8;
    bf16x8 aq0 = *(const bf16x8*)qp;
    bf16x8 aq1 = *(const bf16x8*)(qp + 32);
    __syncthreads();

    // scores: 16 n-tiles x 16 keys
    const f32x4 fz = {0.f, 0.f, 0.f, 0.f};
    f32x4 s[16];
    #pragma unroll
    for (int nt = 0; nt < 16; nt++) {
        int row = nt * 16 + ln;
        bf16x8 b0 = *(const bf16x8*)(Ks + row * 64 + ((quad       ^ (ln & 7)) * 8));
        bf16x8 b1 = *(const bf16x8*)(Ks + row * 64 + (((4 + quad) ^ (ln & 7)) * 8));
        f32x4 t = mfma16(aq0, b0, fz);
        t = mfma16(aq1, b1, t);
        s[nt] = t;
    }
    __syncthreads();   // all Ks reads done before AOs (alias) writes

    // softmax; row = quad*4+r, col key = wstart + nt*16 + ln
    const float SC = 0.125f * 1.4426950408889634f;   // /sqrt(64) * log2(e)
    float mr[4] = {-INFINITY, -INFINITY, -INFINITY, -INFINITY};
    #pragma unroll
    for (int nt = 0; nt < 16; nt++) {
        int key = wstart + nt * 16 + ln;
        bool valid = (key >= 0) && (key < L_SEQ);
        #pragma unroll
        for (int r = 0; r < 4; r++) {
            float v = valid ? s[nt][r] * SC : -INFINITY;
            s[nt][r] = v;
            mr[r] = fmaxf(mr[r], v);
        }
    }
    #pragma unroll
    for (int off = 1; off < 16; off <<= 1)
        #pragma unroll
        for (int r = 0; r < 4; r++) mr[r] = fmaxf(mr[r], __shfl_xor(mr[r], off));

    float lr[4] = {0.f, 0.f, 0.f, 0.f};
    #pragma unroll
    for (int nt = 0; nt < 16; nt++)
        #pragma unroll
        for (int r = 0; r < 4; r++) {
            float p = exp2f(s[nt][r] - mr[r]);   // exp2(-inf)=0 on masked cols
            s[nt][r] = p;
            lr[r] += p;
        }
    #pragma unroll
    for (int off = 1; off < 16; off <<= 1)
        #pragma unroll
        for (int r = 0; r < 4; r++) lr[r] += __shfl_xor(lr[r], off);
    float rl[4];
    #pragma unroll
    for (int r = 0; r < 4; r++) rl[r] = 1.f / lr[r];

    // PV: per 32-key chunk, C-layout -> A-layout via xor-swizzled per-wave LDS
    u16* pb = pbuf[w];
    f32x4 o[4] = {fz, fz, fz, fz};
    #pragma unroll
    for (int ks = 0; ks < 8; ks++) {
        #pragma unroll
        for (int n2 = 0; n2 < 2; n2++) {
            int nt = ks * 2 + n2;
            #pragma unroll
            for (int r = 0; r < 4; r++)
                pb[(quad * 4 + r) * 32 + ((n2 * 16 + ln) ^ (quad * 8))] = f2bf(s[nt][r]);
        }
        bf16x8 ap = *(const bf16x8*)(pb + ln * 32 + ((quad * 8) ^ (((ln >> 2) & 3) * 8)));
        #pragma unroll
        for (int dt = 0; dt < 4; dt++) {
            int d = dt * 16 + ln;
            bf16x8 vb = *(const bf16x8*)(Vs + d * 256 + (((ks * 4 + quad) ^ (ln & 7)) * 8));
            o[dt] = mfma16(ap, vb, o[dt]);
        }
    }

    // AO through LDS (alias Ks) for coalesced 16B stores
    u16* AOs = Ks;   // [128][72]
    #pragma unroll
    for (int dt = 0; dt < 4; dt++)
        #pragma unroll
        for (int r = 0; r < 4; r++)
            AOs[(w * 16 + quad * 4 + r) * 72 + dt * 16 + ln] = f2bf(o[dt][r] * rl[r]);
    __syncthreads();
    #pragma unroll
    for (int i = 0; i < 2; i++) {
        int c = i * 512 + tid;
        int row = c >> 3, ch = (c & 7) * 8;
        uint4 v = *(const uint4*)(AOs + row * 72 + ch);
        *(uint4*)(AO + (bbase + blk * 128 + row) * DM + h * 64 + ch) = v;
    }
}

// ---------------------------------------------------------------------------
extern "C" void kernel_launch(void* const* d_in, const int* in_sizes, int n_in,
                              void* d_out, int out_size, void* d_ws, size_t ws_size,
                              hipStream_t stream) {
    const float* x  = (const float*)d_in[0];
    const float* wq = (const float*)d_in[1];
    const float* wk = (const float*)d_in[2];
    const float* wv = (const float*)d_in[3];
    const float* wo = (const float*)d_in[4];
    const float* bo = (const float*)d_in[5];
    float* out = (float*)d_out;

    char* ws = (char*)d_ws;
    const size_t MB = 1024 * 1024;
    u16*   xb  = (u16*)ws;                       // 32 MB  [16384][1024] bf16
    u16*   fqk = (u16*)(ws + 32 * MB);           // 64 MB  [16384][2048] bf16 (Q|K)
    u16*   vt  = (u16*)(ws + 96 * MB);           // 32 MB  [2048][8192] bf16 (V^T)
    u16*   wf  = (u16*)(ws + 128 * MB);          // 6 MB   [3072][1024] bf16 (q,k,v stacked)
    float2* rt = (float2*)(ws + 134 * MB);       // 2 MB   [8192][32] cos/sin
    u16*   wob = (u16*)(ws + 136 * MB);          // 2 MB   [1024][1024] bf16
    u16*   aob = xb;   // x dead after fused GEMM; alias attention output over it

    cvt_bf16<<<8192, 256, 0, stream>>>(x, xb, 2097152);
    prep_misc<<<3072, 256, 0, stream>>>(wq, wk, wv, wo, wf, wob, rt);

    gemm_qkv_fused<<<1536, 256, 0, stream>>>(xb, wf, rt, fqk, vt);
    attn<<<dim3(64, 16, 2), 512, 0, stream>>>(fqk, vt, aob);
    gemm_oproj<<<512, 256, 0, stream>>>(aob, wob, bo, out);
}

// Round 8
// 358.611 us; speedup vs baseline: 1.0258x; 1.0258x over previous
//
#include <hip/hip_runtime.h>
#include <cstdint>
#include <math.h>

#define L_SEQ 8192
#define DM    1024
#define NQK   2048          // fused Q,K output width

typedef unsigned short u16;
typedef __bf16 bf16;
typedef bf16  bf16x8 __attribute__((ext_vector_type(8)));
typedef float f32x4  __attribute__((ext_vector_type(4)));

__device__ __forceinline__ u16 f2bf(float f) {
    unsigned u = __float_as_uint(f);
    u += 0x7fffu + ((u >> 16) & 1u);
    return (u16)(u >> 16);
}

__device__ __forceinline__ f32x4 mfma16(bf16x8 a, bf16x8 b, f32x4 c) {
    return __builtin_amdgcn_mfma_f32_16x16x32_bf16(a, b, c, 0, 0, 0);
}

__device__ __forceinline__ void gld_lds16(const u16* g, u16* l) {
    __builtin_amdgcn_global_load_lds((const __attribute__((address_space(1))) void*)g,
                                     (__attribute__((address_space(3))) void*)l,
                                     16, 0, 0);
}

// ---------------- fp32 -> bf16 conversion (8 elems / thread) ----------------
__global__ void cvt_bf16(const float* __restrict__ src, u16* __restrict__ dst, int n8) {
    int i = blockIdx.x * 256 + threadIdx.x;
    if (i >= n8) return;
    const float4* s4 = (const float4*)src;
    float4 a = s4[2 * i], b = s4[2 * i + 1];
    union { uint4 u; u16 h[8]; } r;
    r.h[0] = f2bf(a.x); r.h[1] = f2bf(a.y); r.h[2] = f2bf(a.z); r.h[3] = f2bf(a.w);
    r.h[4] = f2bf(b.x); r.h[5] = f2bf(b.y); r.h[6] = f2bf(b.z); r.h[7] = f2bf(b.w);
    ((uint4*)dst)[i] = r.u;
}

// ---------------- merged prep: 4 weight cvts + RoPE table -------------------
__global__ void prep_misc(const float* __restrict__ wq, const float* __restrict__ wk,
                          const float* __restrict__ wv, const float* __restrict__ wo,
                          u16* __restrict__ wf, u16* __restrict__ wob,
                          float2* __restrict__ rt) {
    int idx = blockIdx.x * 256 + threadIdx.x;      // 0..786431
    if (idx < 524288) {
        int sel = idx >> 17, i = idx & 131071;
        const float* s = sel == 0 ? wq : sel == 1 ? wk : sel == 2 ? wv : wo;
        u16* d        = sel == 0 ? wf : sel == 1 ? wf + 1048576 : sel == 2 ? wf + 2097152 : wob;
        const float4* s4 = (const float4*)s;
        float4 a = s4[2 * i], b = s4[2 * i + 1];
        union { uint4 u; u16 h[8]; } r;
        r.h[0] = f2bf(a.x); r.h[1] = f2bf(a.y); r.h[2] = f2bf(a.z); r.h[3] = f2bf(a.w);
        r.h[4] = f2bf(b.x); r.h[5] = f2bf(b.y); r.h[6] = f2bf(b.z); r.h[7] = f2bf(b.w);
        ((uint4*)d)[i] = r.u;
    } else {
        int j = idx - 524288;                      // 0..262143
        int pos = j >> 5, i = j & 31;
        float invf = exp2f(-0.4152410118609191f * (float)i);   // 10000^(-i/32)
        float s, c;
        sincosf((float)pos * invf, &s, &c);
        rt[j] = make_float2(c, s);
    }
}

// ============================================================================
// GEMM core (round-6 proven, 790 TF plateau): 256M x 128N tile, BK=32,
// 256 threads = 4 waves (2M x 2N), per-wave 128x64, 16x16x32 MFMA.
// LDS 3-buffer (A 3x16KB + B 3x8KB = 72KB) -> 2 blocks/CU.
// Per iter: waitcnt vmcnt(6)+lgkm(0) -> barrier -> ds_read frags(u+1) ||
// stage(u+3) -> MFMA(u). 128B line = 2 rows x 4 k-chunks, chunk-XOR (line&7).
// XCD supertile keeps A(4MB)+B L2-resident.
// ============================================================================

#define STAGE_COMMON()                                                         \
    const int tid = threadIdx.x;                                               \
    const int lane = tid & 63, w = tid >> 6;                                   \
    const int wm = w >> 1, wn = w & 1;                                         \
    const u16* gA[4]; const u16* gB[2];                                        \
    _Pragma("unroll")                                                          \
    for (int i = 0; i < 4; ++i) {                                              \
        int s = i * 256 + tid;                                                 \
        int li = s >> 3, pc = s & 7, lc = pc ^ (li & 7);                       \
        int row = 2 * li + (lc >> 2), kc = lc & 3;                             \
        gA[i] = Ap + (size_t)(m0 + row) * DM + kc * 8;                         \
    }                                                                          \
    _Pragma("unroll")                                                          \
    for (int i = 0; i < 2; ++i) {                                              \
        int s = i * 256 + tid;                                                 \
        int li = s >> 3, pc = s & 7, lc = pc ^ (li & 7);                       \
        int row = 2 * li + (lc >> 2), kc = lc & 3;                             \
        gB[i] = Bp + (size_t)(n0 + row) * DM + kc * 8;                         \
    }                                                                          \
    u16* ldsAt = SAs + tid * 8;                                                \
    u16* ldsBt = SBs + tid * 8;                                                \
    /* prologue: stage tiles 0,1,2 into bufs 0,1,2 */                          \
    _Pragma("unroll")                                                          \
    for (int t3 = 0; t3 < 3; ++t3) {                                           \
        _Pragma("unroll")                                                      \
        for (int i = 0; i < 4; ++i) gld_lds16(gA[i] + t3 * 32, ldsAt + t3 * 8192 + i * 2048); \
        _Pragma("unroll")                                                      \
        for (int i = 0; i < 2; ++i) gld_lds16(gB[i] + t3 * 32, ldsBt + t3 * 4096 + i * 2048); \
    }

#define GEMM16_PRE()                                                           \
    const int quad = lane >> 4, ln = lane & 15;                                \
    const int l7  = (ln >> 1) & 7;                                             \
    const int pcq = ((ln & 1) * 4 + quad) ^ l7;                                \
    const int aBase = (wm * 64 + (ln >> 1)) * 64 + pcq * 8;                    \
    const int bBase = (wn * 32 + (ln >> 1)) * 64 + pcq * 8;                    \
    const f32x4 fz = {0.f, 0.f, 0.f, 0.f};                                     \
    f32x4 acc[8][4];                                                           \
    _Pragma("unroll")                                                          \
    for (int a = 0; a < 8; a++)                                                \
        _Pragma("unroll")                                                      \
        for (int b = 0; b < 4; b++) acc[a][b] = fz;                            \
    bf16x8 fA[2][8], fB[2][4];                                                 \
    __builtin_amdgcn_s_waitcnt(0x0F7C);  /* vmcnt(12): stage(0) landed */      \
    __builtin_amdgcn_s_barrier();                                              \
    __builtin_amdgcn_sched_barrier(0);                                         \
    _Pragma("unroll")                                                          \
    for (int m = 0; m < 8; m++) fA[0][m] = *(const bf16x8*)(SAs + aBase + m * 512); \
    _Pragma("unroll")                                                          \
    for (int n = 0; n < 4; n++) fB[0][n] = *(const bf16x8*)(SBs + bBase + n * 512)

#define QITER(U, WIMM, RD, ST) do {                                            \
    __builtin_amdgcn_s_waitcnt(WIMM);                                          \
    __builtin_amdgcn_sched_barrier(0);                                         \
    __builtin_amdgcn_s_barrier();                                              \
    __builtin_amdgcn_sched_barrier(0);                                         \
    if (RD) {                                                                  \
        _Pragma("unroll")                                                      \
        for (int m = 0; m < 8; m++)                                            \
            fA[(U + 1) & 1][m] = *(const bf16x8*)(SAs + ((U + 1) % 3) * 8192 + aBase + m * 512); \
        _Pragma("unroll")                                                      \
        for (int n = 0; n < 4; n++)                                            \
            fB[(U + 1) & 1][n] = *(const bf16x8*)(SBs + ((U + 1) % 3) * 4096 + bBase + n * 512); \
    }                                                                          \
    if (ST) {                                                                  \
        _Pragma("unroll")                                                      \
        for (int i = 0; i < 4; ++i)                                            \
            gld_lds16(gA[i] + (U + 3) * 32, ldsAt + (U % 3) * 8192 + i * 2048);\
        _Pragma("unroll")                                                      \
        for (int i = 0; i < 2; ++i)                                            \
            gld_lds16(gB[i] + (U + 3) * 32, ldsBt + (U % 3) * 4096 + i * 2048);\
    }                                                                          \
    __builtin_amdgcn_sched_barrier(0);                                         \
    __builtin_amdgcn_s_setprio(1);                                             \
    _Pragma("unroll")                                                          \
    for (int m = 0; m < 8; m++)                                                \
        _Pragma("unroll")                                                      \
        for (int n = 0; n < 4; n++)                                            \
            acc[m][n] = mfma16(fA[(U) & 1][m], fB[(U) & 1][n], acc[m][n]);     \
    __builtin_amdgcn_s_setprio(0);                                             \
    __builtin_amdgcn_sched_barrier(0);                                         \
} while (0)

#define K_LOOP_ALL()                                                           \
    QITER(0,0x0076,1,1);  QITER(1,0x0076,1,1);  QITER(2,0x0076,1,1);           \
    QITER(3,0x0076,1,1);  QITER(4,0x0076,1,1);  QITER(5,0x0076,1,1);           \
    QITER(6,0x0076,1,1);  QITER(7,0x0076,1,1);  QITER(8,0x0076,1,1);           \
    QITER(9,0x0076,1,1);  QITER(10,0x0076,1,1); QITER(11,0x0076,1,1);          \
    QITER(12,0x0076,1,1); QITER(13,0x0076,1,1); QITER(14,0x0076,1,1);          \
    QITER(15,0x0076,1,1); QITER(16,0x0076,1,1); QITER(17,0x0076,1,1);          \
    QITER(18,0x0076,1,1); QITER(19,0x0076,1,1); QITER(20,0x0076,1,1);          \
    QITER(21,0x0076,1,1); QITER(22,0x0076,1,1); QITER(23,0x0076,1,1);          \
    QITER(24,0x0076,1,1); QITER(25,0x0076,1,1); QITER(26,0x0076,1,1);          \
    QITER(27,0x0076,1,1); QITER(28,0x0076,1,1); QITER(29,0x0076,1,0);          \
    QITER(30,0x0070,1,0); QITER(31,0x0070,0,0)

// ---------------- Q|K GEMM: Y = (X*Wq^T | X*Wk^T) with RoPE ------------------
__global__ __launch_bounds__(256, 2) void gemm_qk(
    const u16* __restrict__ X,        // [16384][1024]
    const u16* __restrict__ W,        // [3072][1024] rows: q,k,v stacked
    const float2* __restrict__ rope,  // [8192][32]
    u16* __restrict__ Y)              // [16384][2048]
{
    __shared__ __align__(16) u16 smem[36864];   // 72 KiB
    u16* SAs = smem;
    u16* SBs = smem + 24576;

    // 1024 blocks: per XCD 8m x 16n as 2 supertiles of 8m x 8n
    const int o   = (int)blockIdx.x;
    const int xcd = o & 7;
    const int r   = o >> 3;                     // 0..127
    const int st  = r >> 6;                     // 2 supertiles of 64
    const int t   = r & 63;
    const int m0  = (xcd * 8 + (t & 7)) * 256;
    const int n0  = (st * 8 + (t >> 3)) * 128;  // 0..1920

    const u16* Ap = X;
    const u16* Bp = W;
    STAGE_COMMON();
    GEMM16_PRE();
    K_LOOP_ALL();
    __syncthreads();

    // RoPE: wave covers one head's 64 cols (wn); pair (i,i+32) = nt,nt+2
    #pragma unroll
    for (int mt = 0; mt < 8; mt++)
        #pragma unroll
        for (int reg = 0; reg < 4; reg++) {
            int rg = (m0 + wm * 128 + mt * 16 + quad * 4 + reg) & (L_SEQ - 1);
            const float2* rp = rope + rg * 32;
            #pragma unroll
            for (int nt = 0; nt < 2; nt++) {
                float2 cs = rp[nt * 16 + ln];
                float x1 = acc[mt][nt][reg], x2 = acc[mt][nt + 2][reg];
                acc[mt][nt][reg]     = x1 * cs.x - x2 * cs.y;
                acc[mt][nt + 2][reg] = x2 * cs.x + x1 * cs.y;
            }
        }
    // store via LDS, two 128-row passes
    u16* Es = smem;   // [128][136]
    #pragma unroll
    for (int mh = 0; mh < 2; mh++) {
        if (mh) __syncthreads();
        if (wm == mh) {
            #pragma unroll
            for (int mt = 0; mt < 8; mt++)
                #pragma unroll
                for (int nt = 0; nt < 4; nt++)
                    #pragma unroll
                    for (int reg = 0; reg < 4; reg++)
                        Es[(mt * 16 + quad * 4 + reg) * 136 + wn * 64 + nt * 16 + ln] =
                            f2bf(acc[mt][nt][reg]);
        }
        __syncthreads();
        #pragma unroll
        for (int i = 0; i < 8; i++) {
            int idx = i * 256 + tid;
            int row = idx >> 4, ch = (idx & 15) * 8;
            uint4 v = *(const uint4*)(Es + row * 136 + ch);
            *(uint4*)(Y + (size_t)(m0 + mh * 128 + row) * NQK + n0 + ch) = v;
        }
    }
}

// ---------------- V GEMM: Vt[(b*16+h)*64+d][seq] = (X*Wv^T)^T ----------------
__global__ __launch_bounds__(256, 2) void gemm_v(
    const u16* __restrict__ X,        // [16384][1024]
    const u16* __restrict__ W,        // [3072][1024]
    u16* __restrict__ Vt)             // [2*16*64][8192]
{
    __shared__ __align__(16) u16 smem[36864];   // 72 KiB
    u16* SAs = smem;
    u16* SBs = smem + 24576;

    // 512 blocks: one 8m x 8n supertile per XCD; n covers W rows 2048..3071
    const int o   = (int)blockIdx.x;
    const int xcd = o & 7;
    const int t   = o >> 3;                     // 0..63
    const int m0  = (xcd * 8 + (t & 7)) * 256;
    const int n0  = 2048 + (t >> 3) * 128;

    const u16* Ap = X;
    const u16* Bp = W;
    STAGE_COMMON();
    GEMM16_PRE();
    K_LOOP_ALL();
    __syncthreads();

    // store TRANSPOSED. Two row-half passes: Es[col][row]
    u16* Es = smem;   // [128][136]
    const int bb = m0 >> 13, seq0 = m0 & (L_SEQ - 1);
    #pragma unroll
    for (int rh = 0; rh < 2; rh++) {
        if (rh) __syncthreads();
        if (wm == rh) {
            #pragma unroll
            for (int mt = 0; mt < 8; mt++)
                #pragma unroll
                for (int nt = 0; nt < 4; nt++)
                    #pragma unroll
                    for (int reg = 0; reg < 4; reg++)
                        Es[(wn * 64 + nt * 16 + ln) * 136 + mt * 16 + quad * 4 + reg] =
                            f2bf(acc[mt][nt][reg]);
        }
        __syncthreads();
        #pragma unroll
        for (int i = 0; i < 8; i++) {
            int idx = i * 256 + tid;
            int dr = idx >> 4, ch = (idx & 15) * 8;
            int gc = n0 - 2048 + dr;           // global V col = h*64 + d
            uint4 v = *(const uint4*)(Es + dr * 136 + ch);
            *(uint4*)(Vt + (size_t)(bb * 1024 + gc) * L_SEQ + seq0 + rh * 128 + ch) = v;
        }
    }
}

// ---------------- Output projection: Out = A * Wo^T + bo, fp32 out ----------
__global__ __launch_bounds__(256, 2) void gemm_oproj(
    const u16* __restrict__ A,        // [16384][1024] bf16
    const u16* __restrict__ Wo,       // [1024][1024] bf16
    const float* __restrict__ bias,
    float* __restrict__ Out)
{
    __shared__ __align__(16) u16 smem[36864];   // 72 KiB
    u16* SAs = smem;
    u16* SBs = smem + 24576;

    // 512 blocks: one 8m x 4n supertile per XCD
    const int o   = (int)blockIdx.x;
    const int xcd = o & 7;
    const int t   = o >> 3;                     // 0..63
    const int m0  = (xcd * 8 + (t & 7)) * 256;
    const int n0  = (t >> 3) * 128;

    const u16* Ap = A;
    const u16* Bp = Wo;
    STAGE_COMMON();
    GEMM16_PRE();
    K_LOOP_ALL();
    __syncthreads();

    // epilogue: bias + fp32 store via LDS, four 64-row passes
    float b4[4];
    #pragma unroll
    for (int nt = 0; nt < 4; nt++) b4[nt] = bias[n0 + wn * 64 + nt * 16 + ln];

    float* Ef = (float*)smem;   // [64][132]
    #pragma unroll
    for (int mq = 0; mq < 4; mq++) {
        if (mq) __syncthreads();
        if (wm == (mq >> 1)) {
            #pragma unroll
            for (int mt = 0; mt < 4; mt++)
                #pragma unroll
                for (int nt = 0; nt < 4; nt++)
                    #pragma unroll
                    for (int reg = 0; reg < 4; reg++)
                        Ef[(mt * 16 + quad * 4 + reg) * 132 + wn * 64 + nt * 16 + ln] =
                            acc[(mq & 1) * 4 + mt][nt][reg] + b4[nt];
        }
        __syncthreads();
        #pragma unroll
        for (int i = 0; i < 8; i++) {
            int idx = i * 256 + tid;
            int row = idx >> 5, ch = (idx & 31) * 4;
            float4 v = *(const float4*)(Ef + row * 132 + ch);
            *(float4*)(Out + (size_t)(m0 + mq * 64 + row) * DM + n0 + ch) = v;
        }
    }
}

// ---------------- Windowed attention ----------------------------------------
// WG = 512 threads / 8 waves = 128 queries x 1 head. grid (64, 16, 2).
// Split-wait staging: Q->regs first, K stage, V stage; vmcnt(4)+barrier lets
// QK^T + softmax run while V lands; V drained at the post-softmax barrier.
__global__ __launch_bounds__(512, 4) void attn(
    const u16* __restrict__ QK,       // [16384][2048]
    const u16* __restrict__ Vt,       // [2048][8192]
    u16* __restrict__ AO)             // [16384][1024]
{
    __shared__ __align__(16) u16 Ks[256 * 64];     // [key][dim-chunk swizzled] 32KB (aliased by AOs)
    __shared__ __align__(16) u16 Vs[64 * 256];     // [dim][key-chunk swizzled] 32KB
    __shared__ __align__(16) u16 pbuf[8][512];     // per-wave P chunk, xor-swizzled

    const int blk = blockIdx.x;
    const int h   = blockIdx.y;
    const int b   = blockIdx.z;
    const int tid = threadIdx.x;
    const int lane = tid & 63, w = tid >> 6;
    const int quad = lane >> 4, ln = lane & 15;
    const int wstart = blk * 128 - 64;
    const size_t bbase = (size_t)b * L_SEQ;

    const u16* Kg = QK + 1024 + h * 64;
    const u16* Vg = Vt + (size_t)(b * 1024 + h * 64) * L_SEQ;

    // Q fragments first (A-layout: m=ln, k=quad*8+j), then K, then V
    const int qrow = blk * 128 + w * 16 + ln;
    const u16* qp = QK + (bbase + qrow) * NQK + h * 64 + quad * 8;
    bf16x8 aq0 = *(const bf16x8*)qp;
    bf16x8 aq1 = *(const bf16x8*)(qp + 32);

    // stage K: 256 rows x 8 chunks, chunk cg = cl ^ (row&7)
    #pragma unroll
    for (int i = 0; i < 4; i++) {
        int c = i * 512 + tid;
        int row = c >> 3, cl = c & 7, cg = cl ^ (row & 7);
        int kr = wstart + row;
        kr = kr < 0 ? 0 : (kr > L_SEQ - 1 ? L_SEQ - 1 : kr);
        gld_lds16(Kg + (size_t)(bbase + kr) * NQK + cg * 8, Ks + c * 8);
    }
    // stage V^T: 64 dim-rows x 32 key-chunks, chunk cg = kc ^ (d&7)
    #pragma unroll
    for (int i = 0; i < 4; i++) {
        int c = i * 512 + tid;
        int d = c >> 5, kc = c & 31, cg = kc ^ (d & 7);
        int key = wstart + cg * 8;
        key = key < 0 ? 0 : (key > L_SEQ - 8 ? L_SEQ - 8 : key);
        gld_lds16(Vg + (size_t)d * L_SEQ + key, Vs + c * 8);
    }

    // K landed (V's 4 loads may still be in flight); Q regs are older -> done
    __builtin_amdgcn_s_waitcnt(0x0F74);   // vmcnt(4), lgkm no-wait
    __builtin_amdgcn_s_barrier();
    __builtin_amdgcn_sched_barrier(0);

    // scores: 16 n-tiles x 16 keys
    const f32x4 fz = {0.f, 0.f, 0.f, 0.f};
    f32x4 s[16];
    __builtin_amdgcn_s_setprio(1);
    #pragma unroll
    for (int nt = 0; nt < 16; nt++) {
        int row = nt * 16 + ln;
        bf16x8 b0 = *(const bf16x8*)(Ks + row * 64 + ((quad       ^ (ln & 7)) * 8));
        bf16x8 b1 = *(const bf16x8*)(Ks + row * 64 + (((4 + quad) ^ (ln & 7)) * 8));
        f32x4 t = mfma16(aq0, b0, fz);
        t = mfma16(aq1, b1, t);
        s[nt] = t;
    }
    __builtin_amdgcn_s_setprio(0);

    // softmax; row = quad*4+r, col key = wstart + nt*16 + ln   (V still landing)
    const float SC = 0.125f * 1.4426950408889634f;   // /sqrt(64) * log2(e)
    float mr[4] = {-INFINITY, -INFINITY, -INFINITY, -INFINITY};
    #pragma unroll
    for (int nt = 0; nt < 16; nt++) {
        int key = wstart + nt * 16 + ln;
        bool valid = (key >= 0) && (key < L_SEQ);
        #pragma unroll
        for (int r = 0; r < 4; r++) {
            float v = valid ? s[nt][r] * SC : -INFINITY;
            s[nt][r] = v;
            mr[r] = fmaxf(mr[r], v);
        }
    }
    #pragma unroll
    for (int off = 1; off < 16; off <<= 1)
        #pragma unroll
        for (int r = 0; r < 4; r++) mr[r] = fmaxf(mr[r], __shfl_xor(mr[r], off));

    float lr[4] = {0.f, 0.f, 0.f, 0.f};
    #pragma unroll
    for (int nt = 0; nt < 16; nt++)
        #pragma unroll
        for (int r = 0; r < 4; r++) {
            float p = exp2f(s[nt][r] - mr[r]);   // exp2(-inf)=0 on masked cols
            s[nt][r] = p;
            lr[r] += p;
        }
    #pragma unroll
    for (int off = 1; off < 16; off <<= 1)
        #pragma unroll
        for (int r = 0; r < 4; r++) lr[r] += __shfl_xor(lr[r], off);
    float rl[4];
    #pragma unroll
    for (int r = 0; r < 4; r++) rl[r] = 1.f / lr[r];

    // V landed + all waves' Ks reads retired (safe for later AOs alias writes)
    __builtin_amdgcn_s_waitcnt(0x0F70);   // vmcnt(0)
    __builtin_amdgcn_s_barrier();
    __builtin_amdgcn_sched_barrier(0);

    // PV: per 32-key chunk, C-layout -> A-layout via xor-swizzled per-wave LDS
    u16* pb = pbuf[w];
    f32x4 o[4] = {fz, fz, fz, fz};
    __builtin_amdgcn_s_setprio(1);
    #pragma unroll
    for (int ks = 0; ks < 8; ks++) {
        #pragma unroll
        for (int n2 = 0; n2 < 2; n2++) {
            int nt = ks * 2 + n2;
            #pragma unroll
            for (int r = 0; r < 4; r++)
                pb[(quad * 4 + r) * 32 + ((n2 * 16 + ln) ^ (quad * 8))] = f2bf(s[nt][r]);
        }
        bf16x8 ap = *(const bf16x8*)(pb + ln * 32 + ((quad * 8) ^ (((ln >> 2) & 3) * 8)));
        #pragma unroll
        for (int dt = 0; dt < 4; dt++) {
            int d = dt * 16 + ln;
            bf16x8 vb = *(const bf16x8*)(Vs + d * 256 + (((ks * 4 + quad) ^ (ln & 7)) * 8));
            o[dt] = mfma16(ap, vb, o[dt]);
        }
    }
    __builtin_amdgcn_s_setprio(0);

    // AO through LDS (alias Ks) for coalesced 16B stores
    u16* AOs = Ks;   // [128][72]
    #pragma unroll
    for (int dt = 0; dt < 4; dt++)
        #pragma unroll
        for (int r = 0; r < 4; r++)
            AOs[(w * 16 + quad * 4 + r) * 72 + dt * 16 + ln] = f2bf(o[dt][r] * rl[r]);
    __syncthreads();
    #pragma unroll
    for (int i = 0; i < 2; i++) {
        int c = i * 512 + tid;
        int row = c >> 3, ch = (c & 7) * 8;
        uint4 v = *(const uint4*)(AOs + row * 72 + ch);
        *(uint4*)(AO + (bbase + blk * 128 + row) * DM + h * 64 + ch) = v;
    }
}

// ---------------------------------------------------------------------------
extern "C" void kernel_launch(void* const* d_in, const int* in_sizes, int n_in,
                              void* d_out, int out_size, void* d_ws, size_t ws_size,
                              hipStream_t stream) {
    const float* x  = (const float*)d_in[0];
    const float* wq = (const float*)d_in[1];
    const float* wk = (const float*)d_in[2];
    const float* wv = (const float*)d_in[3];
    const float* wo = (const float*)d_in[4];
    const float* bo = (const float*)d_in[5];
    float* out = (float*)d_out;

    char* ws = (char*)d_ws;
    const size_t MB = 1024 * 1024;
    u16*   xb  = (u16*)ws;                       // 32 MB  [16384][1024] bf16
    u16*   fqk = (u16*)(ws + 32 * MB);           // 64 MB  [16384][2048] bf16 (Q|K)
    u16*   vt  = (u16*)(ws + 96 * MB);           // 32 MB  [2048][8192] bf16 (V^T)
    u16*   wf  = (u16*)(ws + 128 * MB);          // 6 MB   [3072][1024] bf16 (q,k,v stacked)
    float2* rt = (float2*)(ws + 134 * MB);       // 2 MB   [8192][32] cos/sin
    u16*   wob = (u16*)(ws + 136 * MB);          // 2 MB   [1024][1024] bf16
    u16*   aob = xb;   // x dead after V GEMM; alias attention output over it

    cvt_bf16<<<8192, 256, 0, stream>>>(x, xb, 2097152);
    prep_misc<<<3072, 256, 0, stream>>>(wq, wk, wv, wo, wf, wob, rt);

    gemm_qk<<<1024, 256, 0, stream>>>(xb, wf, rt, fqk);
    gemm_v<<<512, 256, 0, stream>>>(xb, wf, vt);
    attn<<<dim3(64, 16, 2), 512, 0, stream>>>(fqk, vt, aob);
    gemm_oproj<<<512, 256, 0, stream>>>(aob, wob, bo, out);
}